// Round 5
// baseline (282.866 us; speedup 1.0000x reference)
//
#include <hip/hip_runtime.h>
#include <cstdint>
#include <cstddef>

#define N_CLS 80
#define TOPK 1000
#define POOL_N 2048
#define MCAP 512
#define BD 1024
#define DTB 128

// ---------------- K1: decode + score + per-class binning -------------------
// Per-thread arithmetic identical to rounds 1-4 (bit-exact, absmax 0.0).
__global__ __launch_bounds__(DTB) void decode_kernel(
    const float* __restrict__ reg, const float* __restrict__ obj,
    const float* __restrict__ cls, const float* __restrict__ grid,
    const float* __restrict__ anch, const float* __restrict__ strd,
    float* __restrict__ boxes, uint2* __restrict__ scs,
    int* __restrict__ gcnt, uint2* __restrict__ gpool, int N) {
  __shared__ __align__(16) float tile[DTB * 84];
  const int tb = blockIdx.x * DTB;
  const int na = min(DTB, N - tb);
  const int nf4 = na * 20;
  const float4* cg = (const float4*)cls + (size_t)tb * 20;
  float4* tf4 = (float4*)tile;
  for (int j = threadIdx.x; j < nf4; j += DTB) {
    int a = j / 20;
    int p = j - a * 20;
    tf4[a * 21 + p] = cg[j];
  }
  __syncthreads();

  const int t = threadIdx.x;
  const int i = tb + t;
  if (i >= N) return;

  const float4 r = ((const float4*)reg)[i];
  const float2 g = ((const float2*)grid)[i];
  const float2 aw = ((const float2*)anch)[i];
  const float st = strd[i];

  float cx = (1.0f / (1.0f + expf(-r.x)) + g.x) * st;
  float cy = (1.0f / (1.0f + expf(-r.y)) + g.y) * st;
  float w = expf(r.z) * aw.x;
  float h = expf(r.w) * aw.y;
  float b0 = fminf(fmaxf((cx - 0.5f * w) / 640.0f, 0.0f), 1.0f);
  float b1 = fminf(fmaxf((cy - 0.5f * h) / 640.0f, 0.0f), 1.0f);
  float b2 = fminf(fmaxf((cx + 0.5f * w) / 640.0f, 0.0f), 1.0f);
  float b3 = fminf(fmaxf((cy + 0.5f * h) / 640.0f, 0.0f), 1.0f);
  float4 bo; bo.x = b0; bo.y = b1; bo.z = b2; bo.w = b3;
  ((float4*)boxes)[i] = bo;

  float x[N_CLS];
#pragma unroll
  for (int q = 0; q < N_CLS / 4; ++q) {
    float4 v = tf4[t * 21 + q];
    x[4 * q + 0] = v.x; x[4 * q + 1] = v.y;
    x[4 * q + 2] = v.z; x[4 * q + 3] = v.w;
  }
  float mx = x[0];
#pragma unroll
  for (int c = 1; c < N_CLS; ++c) mx = fmaxf(mx, x[c]);
  float s = 0.0f;
#pragma unroll
  for (int c = 0; c < N_CLS; ++c) { float e = expf(x[c] - mx); x[c] = e; s += e; }
  float sig = 1.0f / (1.0f + expf(-obj[i]));
  float best = -1.0f; int bc = 0;
#pragma unroll
  for (int c = 0; c < N_CLS; ++c) {
    float q = sig * (x[c] / s);
    if (q > best) { best = q; bc = c; }
  }
  scs[i] = make_uint2(__float_as_uint(best), (unsigned)bc);
  if (best >= 0.001f) {
    int p = atomicAdd(&gcnt[bc], 1);
    if (p < POOL_N) gpool[bc * POOL_N + p] = make_uint2(__float_as_uint(best), (unsigned)i);
  }
}

__device__ __forceinline__ unsigned long long kinit(int w, int m) {
  int lo = w << 6;
  return (m <= lo) ? 0ULL : ((m - lo >= 64) ? ~0ULL : ((1ULL << (m - lo)) - 1ULL));
}

// Serial greedy scan, rotation-by-unroll depth-4 prefetch, no register copies.
// Rows in LDS at stride WP u64; row i has bits only for j>i (lower words = 0),
// so applying all W words unconditionally is exact greedy semantics.
template <int W, int WP>
__device__ __forceinline__ void greedy_scan(
    const unsigned long long* __restrict__ bm, int m, unsigned long long* kout) {
  unsigned long long km[8];
#pragma unroll
  for (int u = 0; u < 8; ++u) km[u] = kinit(u, m);
  unsigned long long buf[4][W];
#pragma unroll
  for (int s = 0; s < 4; ++s) {
    int r = min(s, m - 1);
#pragma unroll
    for (int u = 0; u < W; ++u) buf[s][u] = bm[(size_t)r * WP + u];
  }
#pragma unroll
  for (int w = 0; w < W; ++w) {
    if ((w << 6) < m) {
      for (int b4 = 0; b4 < 64; b4 += 4) {
        if (((w << 6) + b4) >= m) break;
#pragma unroll
        for (int s = 0; s < 4; ++s) {
          int i = (w << 6) + b4 + s;
          if (i < m) {
            if ((km[w] >> (b4 + s)) & 1ULL) {
#pragma unroll
              for (int u = 0; u < W; ++u) km[u] &= ~buf[s][u];
            }
            int nx = i + 4; if (nx >= m) nx = m - 1;
#pragma unroll
            for (int u = 0; u < W; ++u) buf[s][u] = bm[(size_t)nx * WP + u];
          }
        }
      }
    }
  }
#pragma unroll
  for (int u = 0; u < 8; ++u) kout[u] = km[u];
}

// ---- K2 (fused): per-class rank sort + fillers + build + greedy + out -----
__global__ __launch_bounds__(BD) void nms_kernel(
    const float* __restrict__ boxes, const uint2* __restrict__ scs,
    const int* __restrict__ gcnt, const uint2* __restrict__ gpool,
    float* __restrict__ out, int N) {
  const int c = blockIdx.x;
  const int tid = threadIdx.x;

  __shared__ uint2 pool[POOL_N];                     // 16 KB
  __shared__ float svals[TOPK];                      // 4 KB
  __shared__ int sidx[TOPK];                         // 4 KB
  __shared__ __align__(16) float4 bxyz[TOPK];        // 16 KB
  __shared__ __align__(16) unsigned long long ldsB[MCAP * 8];  // 32 KB
  __shared__ unsigned char kp[TOPK];                 // fallback only
  __shared__ unsigned long long kpw[8];
  __shared__ int wsum[BD / 64 + 1];

  const int cnt = min(gcnt[c], POOL_N);
  const int m = min(cnt, TOPK);
  for (int p = tid; p < cnt; p += BD) pool[p] = gpool[c * POOL_N + p];
  __syncthreads();

  // rank sort: value desc, ties -> index asc (== jax.lax.top_k order);
  // total order => independent of nondeterministic bin order.
  for (int e = tid; e < cnt; e += BD) {
    uint2 me = pool[e];
    float v = __uint_as_float(me.x);
    int idx = (int)me.y;
    int r = 0;
#pragma unroll 4
    for (int k = 0; k < cnt; ++k) {
      uint2 q = pool[k];
      float vk = __uint_as_float(q.x);
      r += (int)((vk > v) || (vk == v && (int)q.y < idx));
    }
    if (r < TOPK) { svals[r] = v; sidx[r] = idx; }
  }
  __syncthreads();

  // fillers: lowest-index non-matching anchors, ascending. ONE pass over the
  // first BD=1024 anchors: positives in any prefix <= m, so fillers in the
  // first 1000 >= 1000 - m = M. (m == TOPK => M == 0, no scan needed.)
  const int M = TOPK - m;
  if (M > 0) {
    int i = tid;
    bool f = false;
    if (i < N) {
      uint2 sc = scs[i];
      f = !((int)sc.y == c && __uint_as_float(sc.x) >= 0.001f);
    }
    unsigned long long mk = __ballot(f ? 1 : 0);
    int lane = tid & 63, wv = tid >> 6;
    int pre = __popcll(mk & ((1ULL << lane) - 1ULL));
    if (lane == 0) wsum[wv] = __popcll(mk);
    __syncthreads();
    if (tid == 0) {
      int acc = 0;
      for (int wq = 0; wq < BD / 64; ++wq) { int t2 = wsum[wq]; wsum[wq] = acc; acc += t2; }
    }
    __syncthreads();
    int pos = wsum[wv] + pre;
    if (f && pos < M) sidx[m + pos] = i;
  }
  __syncthreads();

  // gather boxes into LDS
  const float4* bf4 = (const float4*)boxes;
  for (int t = tid; t < TOPK; t += BD) bxyz[t] = bf4[sidx[t]];
  __syncthreads();

  const int W = (m + 63) >> 6;
  const bool fast = (m > 0) && (m <= MCAP) && (W >= 4) && (W <= 6);

  if (fast) {
    const int WP = (W == 4) ? 4 : 6;   // even row stride in u64
    // build upper-triangle iou>0.6 bitmask in LDS (lower-tri words = 0)
    const int tasks = m * W;
    for (int q = tid; q < tasks; q += BD) {
      int w = q / m;                    // adjacent threads -> adjacent rows
      int row = q - w * m;              // => bxyz[j] broadcast in the wave
      unsigned long long bits = 0ULL;
      if (w >= (row >> 6)) {
        float4 rb = bxyz[row];
        float ai = (rb.z - rb.x) * (rb.w - rb.y);
        int j0 = w << 6, jend = min(j0 + 64, m);
        for (int j = max(j0, row + 1); j < jend; ++j) {
          float4 jb = bxyz[j];
          float aj = (jb.z - jb.x) * (jb.w - jb.y);
          float xx1 = fmaxf(rb.x, jb.x), yy1 = fmaxf(rb.y, jb.y);
          float xx2 = fminf(rb.z, jb.z), yy2 = fminf(rb.w, jb.w);
          float ww = fmaxf(1e-28f, xx2 - xx1), hh = fmaxf(1e-28f, yy2 - yy1);
          float inter = ww * hh;
          float iou = inter / (ai + aj - inter + 1e-14f);
          if (iou > 0.6f) bits |= (1ULL << (j - j0));
        }
      }
      ldsB[(size_t)row * WP + w] = bits;
    }
    __syncthreads();
    if (tid < 64) {
      unsigned long long km[8];
      if (W == 4) greedy_scan<4, 4>(ldsB, m, km);
      else if (W == 5) greedy_scan<5, 6>(ldsB, m, km);
      else greedy_scan<6, 6>(ldsB, m, km);
      if (tid == 0) {
#pragma unroll
        for (int u = 0; u < 8; ++u) kpw[u] = km[u];
      }
    }
    __syncthreads();
  } else {
    // fallback (any m <= TOPK): serial barrier loop on bxyz — always correct
    for (int t = tid; t < TOPK; t += BD) kp[t] = (t < m) ? 1 : 0;
    __syncthreads();
    for (int i = 0; i < m; ++i) {
      if (kp[i]) {
        float4 rb = bxyz[i];
        float ai = (rb.z - rb.x) * (rb.w - rb.y);
        for (int j = i + 1 + tid; j < m; j += BD) {
          if (kp[j]) {
            float4 jb = bxyz[j];
            float aj = (jb.z - jb.x) * (jb.w - jb.y);
            float xx1 = fmaxf(rb.x, jb.x), yy1 = fmaxf(rb.y, jb.y);
            float xx2 = fminf(rb.z, jb.z), yy2 = fminf(rb.w, jb.w);
            float ww = fmaxf(1e-28f, xx2 - xx1), hh = fmaxf(1e-28f, yy2 - yy1);
            float inter = ww * hh;
            float iou = inter / (ai + aj - inter + 1e-14f);
            if (iou > 0.6f) kp[j] = 0;
          }
        }
      }
      __syncthreads();
    }
  }

  // outputs: boxes [80,1000,4], scores*keep [80,1000], keep [80,1000]
  float* outB = out;
  float* outS = out + N_CLS * TOPK * 4;
  float* outK = outS + N_CLS * TOPK;
  for (int t = tid; t < TOPK; t += BD) {
    float k = 0.0f;
    if (t < m)
      k = fast ? (float)((kpw[t >> 6] >> (t & 63)) & 1ULL) : (float)kp[t];
    float v = (t < m) ? svals[t] : -1.0f;
    ((float4*)outB)[c * TOPK + t] = bxyz[t];
    outS[c * TOPK + t] = v * k;
    outK[c * TOPK + t] = k;
  }
}

extern "C" void kernel_launch(void* const* d_in, const int* in_sizes, int n_in,
                              void* d_out, int out_size, void* d_ws, size_t ws_size,
                              hipStream_t stream) {
  const float* reg  = (const float*)d_in[0];
  const float* obj  = (const float*)d_in[1];
  const float* cls  = (const float*)d_in[2];
  const float* grid = (const float*)d_in[3];
  const float* anch = (const float*)d_in[4];
  const float* strd = (const float*)d_in[5];
  const int N = in_sizes[0] / 4;  // 25200

  char* w8 = (char*)d_ws;
  size_t off = 0;
  float* boxes = (float*)(w8 + off); off += (size_t)N * 16;
  uint2* scs   = (uint2*)(w8 + off); off += (size_t)N * 8;
  int* gcnt    = (int*)(w8 + off);   off += 512;            // 80 ints, padded
  uint2* gpool = (uint2*)(w8 + off); off += (size_t)N_CLS * POOL_N * 8;
  float* out = (float*)d_out;

  hipMemsetAsync(gcnt, 0, N_CLS * sizeof(int), stream);
  decode_kernel<<<(N + DTB - 1) / DTB, DTB, 0, stream>>>(
      reg, obj, cls, grid, anch, strd, boxes, scs, gcnt, gpool, N);
  nms_kernel<<<N_CLS, BD, 0, stream>>>(boxes, scs, gcnt, gpool, out, N);
}

// Round 6
// 142.695 us; speedup vs baseline: 1.9823x; 1.9823x over previous
//
#include <hip/hip_runtime.h>
#include <cstdint>
#include <cstddef>

#define N_CLS 80
#define TOPK 1000
#define POOL_N 2048
#define MCAP 512
#define BD 1024
#define DTB 128

// ---------------- K1: decode + score + per-class binning -------------------
// Per-thread arithmetic identical to rounds 1-5 (bit-exact, absmax 0.0).
__global__ __launch_bounds__(DTB) void decode_kernel(
    const float* __restrict__ reg, const float* __restrict__ obj,
    const float* __restrict__ cls, const float* __restrict__ grid,
    const float* __restrict__ anch, const float* __restrict__ strd,
    float* __restrict__ boxes, uint2* __restrict__ scs,
    int* __restrict__ gcnt, uint2* __restrict__ gpool, int N) {
  __shared__ __align__(16) float tile[DTB * 84];
  const int tb = blockIdx.x * DTB;
  const int na = min(DTB, N - tb);
  const int nf4 = na * 20;
  const float4* cg = (const float4*)cls + (size_t)tb * 20;
  float4* tf4 = (float4*)tile;
  for (int j = threadIdx.x; j < nf4; j += DTB) {
    int a = j / 20;
    int p = j - a * 20;
    tf4[a * 21 + p] = cg[j];
  }
  __syncthreads();

  const int t = threadIdx.x;
  const int i = tb + t;
  if (i >= N) return;

  const float4 r = ((const float4*)reg)[i];
  const float2 g = ((const float2*)grid)[i];
  const float2 aw = ((const float2*)anch)[i];
  const float st = strd[i];

  float cx = (1.0f / (1.0f + expf(-r.x)) + g.x) * st;
  float cy = (1.0f / (1.0f + expf(-r.y)) + g.y) * st;
  float w = expf(r.z) * aw.x;
  float h = expf(r.w) * aw.y;
  float b0 = fminf(fmaxf((cx - 0.5f * w) / 640.0f, 0.0f), 1.0f);
  float b1 = fminf(fmaxf((cy - 0.5f * h) / 640.0f, 0.0f), 1.0f);
  float b2 = fminf(fmaxf((cx + 0.5f * w) / 640.0f, 0.0f), 1.0f);
  float b3 = fminf(fmaxf((cy + 0.5f * h) / 640.0f, 0.0f), 1.0f);
  float4 bo; bo.x = b0; bo.y = b1; bo.z = b2; bo.w = b3;
  ((float4*)boxes)[i] = bo;

  float x[N_CLS];
#pragma unroll
  for (int q = 0; q < N_CLS / 4; ++q) {
    float4 v = tf4[t * 21 + q];
    x[4 * q + 0] = v.x; x[4 * q + 1] = v.y;
    x[4 * q + 2] = v.z; x[4 * q + 3] = v.w;
  }
  float mx = x[0];
#pragma unroll
  for (int c = 1; c < N_CLS; ++c) mx = fmaxf(mx, x[c]);
  float s = 0.0f;
#pragma unroll
  for (int c = 0; c < N_CLS; ++c) { float e = expf(x[c] - mx); x[c] = e; s += e; }
  float sig = 1.0f / (1.0f + expf(-obj[i]));
  float best = -1.0f; int bc = 0;
#pragma unroll
  for (int c = 0; c < N_CLS; ++c) {
    float q = sig * (x[c] / s);
    if (q > best) { best = q; bc = c; }
  }
  scs[i] = make_uint2(__float_as_uint(best), (unsigned)bc);
  if (best >= 0.001f) {
    int p = atomicAdd(&gcnt[bc], 1);
    if (p < POOL_N) gpool[bc * POOL_N + p] = make_uint2(__float_as_uint(best), (unsigned)i);
  }
}

__device__ __forceinline__ unsigned long long kinit(int w, int m) {
  int lo = w << 6;
  return (m <= lo) ? 0ULL : ((m - lo >= 64) ? ~0ULL : ((1ULL << (m - lo)) - 1ULL));
}

// ---- K2 (fused): per-class rank sort + fillers + build + greedy + out -----
__global__ __launch_bounds__(BD) void nms_kernel(
    const float* __restrict__ boxes, const uint2* __restrict__ scs,
    const int* __restrict__ gcnt, const uint2* __restrict__ gpool,
    float* __restrict__ out, int N) {
  const int c = blockIdx.x;
  const int tid = threadIdx.x;

  __shared__ uint2 pool[POOL_N];                     // 16 KB
  __shared__ float svals[TOPK];                      // 4 KB
  __shared__ int sidx[TOPK];                         // 4 KB
  __shared__ __align__(16) float4 bxyz[TOPK];        // 16 KB
  __shared__ __align__(16) unsigned long long ldsB[MCAP * 8];  // 32 KB, stride 8
  __shared__ unsigned char kp[TOPK];                 // fallback only
  __shared__ unsigned long long kpw[8];
  __shared__ unsigned long long nzw[8];              // per-row nonzero bitmap
  __shared__ int wsum[BD / 64 + 1];

  const int cnt = min(gcnt[c], POOL_N);
  const int m = min(cnt, TOPK);
  for (int p = tid; p < cnt; p += BD) pool[p] = gpool[c * POOL_N + p];
  __syncthreads();

  // rank sort: value desc, ties -> index asc (== jax.lax.top_k order);
  // total order => independent of nondeterministic bin order.
  for (int e = tid; e < cnt; e += BD) {
    uint2 me = pool[e];
    float v = __uint_as_float(me.x);
    int idx = (int)me.y;
    int r = 0;
#pragma unroll 4
    for (int k = 0; k < cnt; ++k) {
      uint2 q = pool[k];
      float vk = __uint_as_float(q.x);
      r += (int)((vk > v) || (vk == v && (int)q.y < idx));
    }
    if (r < TOPK) { svals[r] = v; sidx[r] = idx; }
  }
  __syncthreads();

  // fillers: lowest-index non-matching anchors, ascending. ONE pass over the
  // first BD=1024 anchors: positives in any prefix <= m, so fillers in the
  // first 1000 >= 1000 - m = M.
  const int M = TOPK - m;
  if (M > 0) {
    int i = tid;
    bool f = false;
    if (i < N) {
      uint2 sc = scs[i];
      f = !((int)sc.y == c && __uint_as_float(sc.x) >= 0.001f);
    }
    unsigned long long mk = __ballot(f ? 1 : 0);
    int lane = tid & 63, wv = tid >> 6;
    int pre = __popcll(mk & ((1ULL << lane) - 1ULL));
    if (lane == 0) wsum[wv] = __popcll(mk);
    __syncthreads();
    if (tid == 0) {
      int acc = 0;
      for (int wq = 0; wq < BD / 64; ++wq) { int t2 = wsum[wq]; wsum[wq] = acc; acc += t2; }
    }
    __syncthreads();
    int pos = wsum[wv] + pre;
    if (f && pos < M) sidx[m + pos] = i;
  }
  __syncthreads();

  // gather boxes into LDS
  const float4* bf4 = (const float4*)boxes;
  for (int t = tid; t < TOPK; t += BD) bxyz[t] = bf4[sidx[t]];
  __syncthreads();

  const int W = (m + 63) >> 6;
  const bool fast = (m > 0) && (m <= MCAP);

  if (fast) {
    // build upper-triangle iou>0.6 bitmask in LDS (lower-tri words = 0)
    const int tasks = m * W;
    for (int q = tid; q < tasks; q += BD) {
      int w = q / m;                    // adjacent threads -> adjacent rows
      int row = q - w * m;              // => bxyz[j] broadcast in the wave
      unsigned long long bits = 0ULL;
      if (w >= (row >> 6)) {
        float4 rb = bxyz[row];
        float ai = (rb.z - rb.x) * (rb.w - rb.y);
        int j0 = w << 6, jend = min(j0 + 64, m);
        for (int j = max(j0, row + 1); j < jend; ++j) {
          float4 jb = bxyz[j];
          float aj = (jb.z - jb.x) * (jb.w - jb.y);
          float xx1 = fmaxf(rb.x, jb.x), yy1 = fmaxf(rb.y, jb.y);
          float xx2 = fminf(rb.z, jb.z), yy2 = fminf(rb.w, jb.w);
          float ww = fmaxf(1e-28f, xx2 - xx1), hh = fmaxf(1e-28f, yy2 - yy1);
          float inter = ww * hh;
          float iou = inter / (ai + aj - inter + 1e-14f);
          if (iou > 0.6f) bits |= (1ULL << (j - j0));
        }
      }
      ldsB[(size_t)row * 8 + w] = bits;
    }
    __syncthreads();

    // nz summary: bit per row, set iff the row has any suppression bit.
    // (rows >= m and words >= W never contribute: guarded below)
    if (tid < 512) {
      bool any = false;
      if (tid < m) {
        const unsigned long long* rw = &ldsB[(size_t)tid * 8];
        for (int u = 0; u < W; ++u) any |= (rw[u] != 0ULL);
      }
      unsigned long long bl = __ballot(any ? 1 : 0);
      if ((tid & 63) == 0) nzw[tid >> 6] = bl;
    }
    __syncthreads();

    // serial greedy scan with nz-skip: visit only rows that are still kept
    // AND can suppress something. Applying an all-zero row is a no-op, so
    // skipping nz=0 rows is exact. ~40 VGPRs -> no scratch spill.
    if (tid == 0) {
      unsigned long long km[8];
#pragma unroll
      for (int u = 0; u < 8; ++u) km[u] = kinit(u, m);
#pragma unroll
      for (int w = 0; w < 8; ++w) {
        if ((w << 6) < m) {
          const unsigned long long nzm = nzw[w];
          unsigned long long cand = km[w] & nzm;
          while (cand) {
            int b = __ffsll(cand) - 1;
            const ulonglong2* rp2 =
                (const ulonglong2*)&ldsB[((size_t)((w << 6) + b)) * 8];
            ulonglong2 r0 = rp2[0], r1 = rp2[1], r2 = rp2[2], r3 = rp2[3];
            // words >= W are garbage but km[u>=W]==0, so harmless.
            km[0] &= ~r0.x; km[1] &= ~r0.y; km[2] &= ~r1.x; km[3] &= ~r1.y;
            km[4] &= ~r2.x; km[5] &= ~r2.y; km[6] &= ~r3.x; km[7] &= ~r3.y;
            unsigned long long done = (b >= 63) ? ~0ULL : ((2ULL << b) - 1ULL);
            cand = km[w] & nzm & ~done;
          }
        }
      }
#pragma unroll
      for (int u = 0; u < 8; ++u) kpw[u] = km[u];
    }
    __syncthreads();
  } else {
    // fallback (m == 0 or m > MCAP): serial barrier loop — always correct
    for (int t = tid; t < TOPK; t += BD) kp[t] = (t < m) ? 1 : 0;
    __syncthreads();
    for (int i = 0; i < m; ++i) {
      if (kp[i]) {
        float4 rb = bxyz[i];
        float ai = (rb.z - rb.x) * (rb.w - rb.y);
        for (int j = i + 1 + tid; j < m; j += BD) {
          if (kp[j]) {
            float4 jb = bxyz[j];
            float aj = (jb.z - jb.x) * (jb.w - jb.y);
            float xx1 = fmaxf(rb.x, jb.x), yy1 = fmaxf(rb.y, jb.y);
            float xx2 = fminf(rb.z, jb.z), yy2 = fminf(rb.w, jb.w);
            float ww = fmaxf(1e-28f, xx2 - xx1), hh = fmaxf(1e-28f, yy2 - yy1);
            float inter = ww * hh;
            float iou = inter / (ai + aj - inter + 1e-14f);
            if (iou > 0.6f) kp[j] = 0;
          }
        }
      }
      __syncthreads();
    }
  }

  // outputs: boxes [80,1000,4], scores*keep [80,1000], keep [80,1000]
  float* outB = out;
  float* outS = out + N_CLS * TOPK * 4;
  float* outK = outS + N_CLS * TOPK;
  for (int t = tid; t < TOPK; t += BD) {
    float k = 0.0f;
    if (t < m)
      k = fast ? (float)((kpw[t >> 6] >> (t & 63)) & 1ULL) : (float)kp[t];
    float v = (t < m) ? svals[t] : -1.0f;
    ((float4*)outB)[c * TOPK + t] = bxyz[t];
    outS[c * TOPK + t] = v * k;
    outK[c * TOPK + t] = k;
  }
}

extern "C" void kernel_launch(void* const* d_in, const int* in_sizes, int n_in,
                              void* d_out, int out_size, void* d_ws, size_t ws_size,
                              hipStream_t stream) {
  const float* reg  = (const float*)d_in[0];
  const float* obj  = (const float*)d_in[1];
  const float* cls  = (const float*)d_in[2];
  const float* grid = (const float*)d_in[3];
  const float* anch = (const float*)d_in[4];
  const float* strd = (const float*)d_in[5];
  const int N = in_sizes[0] / 4;  // 25200

  char* w8 = (char*)d_ws;
  size_t off = 0;
  float* boxes = (float*)(w8 + off); off += (size_t)N * 16;
  uint2* scs   = (uint2*)(w8 + off); off += (size_t)N * 8;
  int* gcnt    = (int*)(w8 + off);   off += 512;            // 80 ints, padded
  uint2* gpool = (uint2*)(w8 + off); off += (size_t)N_CLS * POOL_N * 8;
  float* out = (float*)d_out;

  hipMemsetAsync(gcnt, 0, N_CLS * sizeof(int), stream);
  decode_kernel<<<(N + DTB - 1) / DTB, DTB, 0, stream>>>(
      reg, obj, cls, grid, anch, strd, boxes, scs, gcnt, gpool, N);
  nms_kernel<<<N_CLS, BD, 0, stream>>>(boxes, scs, gcnt, gpool, out, N);
}

// Round 7
// 141.295 us; speedup vs baseline: 2.0020x; 1.0099x over previous
//
#include <hip/hip_runtime.h>
#include <cstdint>
#include <cstddef>

#define N_CLS 80
#define TOPK 1000
#define POOL_N 2048
#define MCAP 512
#define BD 1024
#define DTB 128

// ---------------- K1: decode + score + per-class binning -------------------
// Softmax/argmax arithmetic: identical op sequence to rounds 1-6 but with the
// per-thread x[80] array replaced by 3 recompute passes over the LDS tile
// (expf is deterministic => bit-exact, absmax 0.0). Kills the scratch spill
// that made decode ~54 us (VGPR_Count was 88 with an 80-float array).
__global__ __launch_bounds__(DTB) void decode_kernel(
    const float* __restrict__ reg, const float* __restrict__ obj,
    const float* __restrict__ cls, const float* __restrict__ grid,
    const float* __restrict__ anch, const float* __restrict__ strd,
    float* __restrict__ boxes, uint2* __restrict__ scs,
    int* __restrict__ gcnt, uint2* __restrict__ gpool, int N) {
  __shared__ __align__(16) float tile[DTB * 84];
  const int tb = blockIdx.x * DTB;
  const int na = min(DTB, N - tb);
  const int nf4 = na * 20;
  const float4* cg = (const float4*)cls + (size_t)tb * 20;
  float4* tf4 = (float4*)tile;
  for (int j = threadIdx.x; j < nf4; j += DTB) {
    int a = j / 20;
    int p = j - a * 20;
    tf4[a * 21 + p] = cg[j];
  }
  __syncthreads();

  const int t = threadIdx.x;
  const int i = tb + t;
  if (i >= N) return;

  const float4 r = ((const float4*)reg)[i];
  const float2 g = ((const float2*)grid)[i];
  const float2 aw = ((const float2*)anch)[i];
  const float st = strd[i];

  float cx = (1.0f / (1.0f + expf(-r.x)) + g.x) * st;
  float cy = (1.0f / (1.0f + expf(-r.y)) + g.y) * st;
  float w = expf(r.z) * aw.x;
  float h = expf(r.w) * aw.y;
  float b0 = fminf(fmaxf((cx - 0.5f * w) / 640.0f, 0.0f), 1.0f);
  float b1 = fminf(fmaxf((cy - 0.5f * h) / 640.0f, 0.0f), 1.0f);
  float b2 = fminf(fmaxf((cx + 0.5f * w) / 640.0f, 0.0f), 1.0f);
  float b3 = fminf(fmaxf((cy + 0.5f * h) / 640.0f, 0.0f), 1.0f);
  float4 bo; bo.x = b0; bo.y = b1; bo.z = b2; bo.w = b3;
  ((float4*)boxes)[i] = bo;

  const float4* row = tf4 + t * 21;

  // pass A: running max, exact original op order (x[0]; fmaxf chain c=1..79)
  float mx;
  {
    float4 v = row[0];
    mx = v.x;
    mx = fmaxf(mx, v.y); mx = fmaxf(mx, v.z); mx = fmaxf(mx, v.w);
#pragma unroll
    for (int q = 1; q < N_CLS / 4; ++q) {
      float4 u = row[q];
      mx = fmaxf(mx, u.x); mx = fmaxf(mx, u.y);
      mx = fmaxf(mx, u.z); mx = fmaxf(mx, u.w);
    }
  }
  // pass B: s = sum expf(x-mx), same accumulation order
  float s = 0.0f;
#pragma unroll
  for (int q = 0; q < N_CLS / 4; ++q) {
    float4 u = row[q];
    s += expf(u.x - mx); s += expf(u.y - mx);
    s += expf(u.z - mx); s += expf(u.w - mx);
  }
  // pass C: first-occurrence argmax of q = sig*(e/s), identical expression
  float sig = 1.0f / (1.0f + expf(-obj[i]));
  float best = -1.0f; int bc = 0;
#pragma unroll
  for (int q = 0; q < N_CLS / 4; ++q) {
    float4 u = row[q];
    float e0 = expf(u.x - mx), e1 = expf(u.y - mx);
    float e2 = expf(u.z - mx), e3 = expf(u.w - mx);
    float q0 = sig * (e0 / s);
    if (q0 > best) { best = q0; bc = 4 * q + 0; }
    float q1 = sig * (e1 / s);
    if (q1 > best) { best = q1; bc = 4 * q + 1; }
    float q2 = sig * (e2 / s);
    if (q2 > best) { best = q2; bc = 4 * q + 2; }
    float q3 = sig * (e3 / s);
    if (q3 > best) { best = q3; bc = 4 * q + 3; }
  }
  scs[i] = make_uint2(__float_as_uint(best), (unsigned)bc);
  if (best >= 0.001f) {
    int p = atomicAdd(&gcnt[bc], 1);
    if (p < POOL_N) gpool[bc * POOL_N + p] = make_uint2(__float_as_uint(best), (unsigned)i);
  }
}

__device__ __forceinline__ unsigned long long kinit(int w, int m) {
  int lo = w << 6;
  return (m <= lo) ? 0ULL : ((m - lo >= 64) ? ~0ULL : ((1ULL << (m - lo)) - 1ULL));
}

// ---- K2 (fused): per-class rank sort + fillers + build + greedy + out -----
__global__ __launch_bounds__(BD) void nms_kernel(
    const float* __restrict__ boxes, const uint2* __restrict__ scs,
    const int* __restrict__ gcnt, const uint2* __restrict__ gpool,
    float* __restrict__ out, int N) {
  const int c = blockIdx.x;
  const int tid = threadIdx.x;

  __shared__ uint2 pool[POOL_N];                     // 16 KB
  __shared__ float svals[TOPK];                      // 4 KB
  __shared__ int sidx[TOPK];                         // 4 KB
  __shared__ __align__(16) float4 bxyz[TOPK];        // 16 KB
  __shared__ __align__(16) unsigned long long ldsB[MCAP * 8];  // 32 KB, stride 8
  __shared__ unsigned char kp[TOPK];                 // fallback only
  __shared__ unsigned long long kpw[8];
  __shared__ unsigned long long nzw[8];              // per-row nonzero bitmap
  __shared__ int wsum[BD / 64 + 1];

  const int cnt = min(gcnt[c], POOL_N);
  const int m = min(cnt, TOPK);
  for (int p = tid; p < cnt; p += BD) pool[p] = gpool[c * POOL_N + p];
  __syncthreads();

  // rank sort: value desc, ties -> index asc (== jax.lax.top_k order);
  // total order => independent of nondeterministic bin order.
  for (int e = tid; e < cnt; e += BD) {
    uint2 me = pool[e];
    float v = __uint_as_float(me.x);
    int idx = (int)me.y;
    int r = 0;
#pragma unroll 4
    for (int k = 0; k < cnt; ++k) {
      uint2 q = pool[k];
      float vk = __uint_as_float(q.x);
      r += (int)((vk > v) || (vk == v && (int)q.y < idx));
    }
    if (r < TOPK) { svals[r] = v; sidx[r] = idx; }
  }
  __syncthreads();

  // fillers: lowest-index non-matching anchors, ascending. ONE pass over the
  // first BD=1024 anchors: positives in any prefix <= m, so fillers in the
  // first 1000 >= 1000 - m = M.
  const int M = TOPK - m;
  if (M > 0) {
    int i = tid;
    bool f = false;
    if (i < N) {
      uint2 sc = scs[i];
      f = !((int)sc.y == c && __uint_as_float(sc.x) >= 0.001f);
    }
    unsigned long long mk = __ballot(f ? 1 : 0);
    int lane = tid & 63, wv = tid >> 6;
    int pre = __popcll(mk & ((1ULL << lane) - 1ULL));
    if (lane == 0) wsum[wv] = __popcll(mk);
    __syncthreads();
    if (tid == 0) {
      int acc = 0;
      for (int wq = 0; wq < BD / 64; ++wq) { int t2 = wsum[wq]; wsum[wq] = acc; acc += t2; }
    }
    __syncthreads();
    int pos = wsum[wv] + pre;
    if (f && pos < M) sidx[m + pos] = i;
  }
  __syncthreads();

  // gather boxes into LDS
  const float4* bf4 = (const float4*)boxes;
  for (int t = tid; t < TOPK; t += BD) bxyz[t] = bf4[sidx[t]];
  __syncthreads();

  const int W = (m + 63) >> 6;
  const bool fast = (m > 0) && (m <= MCAP);

  if (fast) {
    // build upper-triangle iou>0.6 bitmask in LDS (lower-tri words = 0)
    const int tasks = m * W;
    for (int q = tid; q < tasks; q += BD) {
      int w = q / m;                    // adjacent threads -> adjacent rows
      int row = q - w * m;              // => bxyz[j] broadcast in the wave
      unsigned long long bits = 0ULL;
      if (w >= (row >> 6)) {
        float4 rb = bxyz[row];
        float ai = (rb.z - rb.x) * (rb.w - rb.y);
        int j0 = w << 6, jend = min(j0 + 64, m);
        for (int j = max(j0, row + 1); j < jend; ++j) {
          float4 jb = bxyz[j];
          float aj = (jb.z - jb.x) * (jb.w - jb.y);
          float xx1 = fmaxf(rb.x, jb.x), yy1 = fmaxf(rb.y, jb.y);
          float xx2 = fminf(rb.z, jb.z), yy2 = fminf(rb.w, jb.w);
          float ww = fmaxf(1e-28f, xx2 - xx1), hh = fmaxf(1e-28f, yy2 - yy1);
          float inter = ww * hh;
          float iou = inter / (ai + aj - inter + 1e-14f);
          if (iou > 0.6f) bits |= (1ULL << (j - j0));
        }
      }
      ldsB[(size_t)row * 8 + w] = bits;
    }
    __syncthreads();

    // nz summary: bit per row, set iff the row has any suppression bit.
    if (tid < 512) {
      bool any = false;
      if (tid < m) {
        const unsigned long long* rw = &ldsB[(size_t)tid * 8];
        for (int u = 0; u < W; ++u) any |= (rw[u] != 0ULL);
      }
      unsigned long long bl = __ballot(any ? 1 : 0);
      if ((tid & 63) == 0) nzw[tid >> 6] = bl;
    }
    __syncthreads();

    // serial greedy scan with nz-skip: visit only rows that are still kept
    // AND can suppress something. Applying an all-zero row is a no-op, so
    // skipping nz=0 rows is exact. ~40 VGPRs -> no scratch spill.
    if (tid == 0) {
      unsigned long long km[8];
#pragma unroll
      for (int u = 0; u < 8; ++u) km[u] = kinit(u, m);
#pragma unroll
      for (int w = 0; w < 8; ++w) {
        if ((w << 6) < m) {
          const unsigned long long nzm = nzw[w];
          unsigned long long cand = km[w] & nzm;
          while (cand) {
            int b = __ffsll(cand) - 1;
            const ulonglong2* rp2 =
                (const ulonglong2*)&ldsB[((size_t)((w << 6) + b)) * 8];
            ulonglong2 r0 = rp2[0], r1 = rp2[1], r2 = rp2[2], r3 = rp2[3];
            // words >= W are garbage but km[u>=W]==0, so harmless.
            km[0] &= ~r0.x; km[1] &= ~r0.y; km[2] &= ~r1.x; km[3] &= ~r1.y;
            km[4] &= ~r2.x; km[5] &= ~r2.y; km[6] &= ~r3.x; km[7] &= ~r3.y;
            unsigned long long done = (b >= 63) ? ~0ULL : ((2ULL << b) - 1ULL);
            cand = km[w] & nzm & ~done;
          }
        }
      }
#pragma unroll
      for (int u = 0; u < 8; ++u) kpw[u] = km[u];
    }
    __syncthreads();
  } else {
    // fallback (m == 0 or m > MCAP): serial barrier loop — always correct
    for (int t = tid; t < TOPK; t += BD) kp[t] = (t < m) ? 1 : 0;
    __syncthreads();
    for (int i = 0; i < m; ++i) {
      if (kp[i]) {
        float4 rb = bxyz[i];
        float ai = (rb.z - rb.x) * (rb.w - rb.y);
        for (int j = i + 1 + tid; j < m; j += BD) {
          if (kp[j]) {
            float4 jb = bxyz[j];
            float aj = (jb.z - jb.x) * (jb.w - jb.y);
            float xx1 = fmaxf(rb.x, jb.x), yy1 = fmaxf(rb.y, jb.y);
            float xx2 = fminf(rb.z, jb.z), yy2 = fminf(rb.w, jb.w);
            float ww = fmaxf(1e-28f, xx2 - xx1), hh = fmaxf(1e-28f, yy2 - yy1);
            float inter = ww * hh;
            float iou = inter / (ai + aj - inter + 1e-14f);
            if (iou > 0.6f) kp[j] = 0;
          }
        }
      }
      __syncthreads();
    }
  }

  // outputs: boxes [80,1000,4], scores*keep [80,1000], keep [80,1000]
  float* outB = out;
  float* outS = out + N_CLS * TOPK * 4;
  float* outK = outS + N_CLS * TOPK;
  for (int t = tid; t < TOPK; t += BD) {
    float k = 0.0f;
    if (t < m)
      k = fast ? (float)((kpw[t >> 6] >> (t & 63)) & 1ULL) : (float)kp[t];
    float v = (t < m) ? svals[t] : -1.0f;
    ((float4*)outB)[c * TOPK + t] = bxyz[t];
    outS[c * TOPK + t] = v * k;
    outK[c * TOPK + t] = k;
  }
}

extern "C" void kernel_launch(void* const* d_in, const int* in_sizes, int n_in,
                              void* d_out, int out_size, void* d_ws, size_t ws_size,
                              hipStream_t stream) {
  const float* reg  = (const float*)d_in[0];
  const float* obj  = (const float*)d_in[1];
  const float* cls  = (const float*)d_in[2];
  const float* grid = (const float*)d_in[3];
  const float* anch = (const float*)d_in[4];
  const float* strd = (const float*)d_in[5];
  const int N = in_sizes[0] / 4;  // 25200

  char* w8 = (char*)d_ws;
  size_t off = 0;
  float* boxes = (float*)(w8 + off); off += (size_t)N * 16;
  uint2* scs   = (uint2*)(w8 + off); off += (size_t)N * 8;
  int* gcnt    = (int*)(w8 + off);   off += 512;            // 80 ints, padded
  uint2* gpool = (uint2*)(w8 + off); off += (size_t)N_CLS * POOL_N * 8;
  float* out = (float*)d_out;

  hipMemsetAsync(gcnt, 0, N_CLS * sizeof(int), stream);
  decode_kernel<<<(N + DTB - 1) / DTB, DTB, 0, stream>>>(
      reg, obj, cls, grid, anch, strd, boxes, scs, gcnt, gpool, N);
  nms_kernel<<<N_CLS, BD, 0, stream>>>(boxes, scs, gcnt, gpool, out, N);
}